// Round 1
// baseline (261.069 us; speedup 1.0000x reference)
//
#include <hip/hip_runtime.h>
#include <cstdint>
#include <cstddef>

// ---------------------------------------------------------------------------
// AttnBlock: GN -> q,k,v conv1x1 -> scaled QK^T softmax -> PV -> proj + resid
// b=16 batches, C=512, HW=1024, fp32 in/out, bf16 MFMA internally.
// All GEMMs in NT form: D[m][n] = sum_k A[m][k] * Bt[n][k]
// ---------------------------------------------------------------------------

typedef __bf16 bf16x8 __attribute__((ext_vector_type(8)));
typedef float f32x4 __attribute__((ext_vector_type(4)));

typedef __attribute__((address_space(1))) const void gl_void;
typedef __attribute__((address_space(3))) void lds_void;

// global -> LDS async copy, 16B per lane. LDS dest is wave-uniform base,
// HW deposits at base + lane*16.
#define GLD16(g, l)                                                     \
  __builtin_amdgcn_global_load_lds((gl_void*)(uintptr_t)(g),            \
                                   (lds_void*)(uintptr_t)(l), 16, 0, 0)

__device__ __forceinline__ unsigned short f2bf(float f) {
  unsigned int u = __builtin_bit_cast(unsigned int, f);
  u += 0x7fffu + ((u >> 16) & 1u);  // round-to-nearest-even
  return (unsigned short)(u >> 16);
}

// ------------------------- weight fp32 -> bf16 -----------------------------
__global__ __launch_bounds__(256) void conv_w_kernel(
    const float* __restrict__ w0, const float* __restrict__ w1,
    const float* __restrict__ w2, const float* __restrict__ w3,
    unsigned short* __restrict__ o0, unsigned short* __restrict__ o1,
    unsigned short* __restrict__ o2, unsigned short* __restrict__ o3) {
  int idx = blockIdx.x * 256 + threadIdx.x;  // 262144 = 512*512
  o0[idx] = f2bf(w0[idx]);
  o1[idx] = f2bf(w1[idx]);
  o2[idx] = f2bf(w2[idx]);
  o3[idx] = f2bf(w3[idx]);
}

// ------------------------- GroupNorm -> hT bf16 ----------------------------
// x: [16][512][1024] fp32.  One block per (b, g): 16*32 = 512 blocks.
// Writes hT[b][i][c] (i=hw index, c=channel) bf16, i.e. transposed.
__global__ __launch_bounds__(256) void gn_kernel(
    const float* __restrict__ x, const float* __restrict__ gsc,
    const float* __restrict__ gbi, unsigned short* __restrict__ hT) {
  const int b = blockIdx.x >> 5;
  const int g = blockIdx.x & 31;
  const int t = threadIdx.x;
  const int wid = t >> 6, lane = t & 63;
  const float* xp = x + ((size_t)(b * 512 + g * 16)) * 1024;

  float s = 0.f, s2 = 0.f;
#pragma unroll 8
  for (int e = 0; e < 64; ++e) {
    float v = xp[e * 256 + t];
    s += v;
    s2 += v * v;
  }
  __shared__ float red[2][4];
#pragma unroll
  for (int off = 32; off > 0; off >>= 1) {
    s += __shfl_down(s, off);
    s2 += __shfl_down(s2, off);
  }
  if (lane == 0) { red[0][wid] = s; red[1][wid] = s2; }
  __syncthreads();
  const float S = red[0][0] + red[0][1] + red[0][2] + red[0][3];
  const float S2 = red[1][0] + red[1][1] + red[1][2] + red[1][3];
  const float mean = S * (1.f / 16384.f);
  const float var = S2 * (1.f / 16384.f) - mean * mean;
  const float rstd = rsqrtf(var + 1e-6f);

  float sc[16], bi[16];
#pragma unroll
  for (int c = 0; c < 16; ++c) {
    sc[c] = gsc[g * 16 + c] * rstd;
    bi[c] = gbi[g * 16 + c] - mean * sc[c];
  }
  unsigned short* hp = hT + (size_t)b * 1024 * 512 + g * 16;
#pragma unroll
  for (int ii = 0; ii < 4; ++ii) {
    int i = ii * 256 + t;
    unsigned int pk[8];
#pragma unroll
    for (int c = 0; c < 8; ++c) {
      float v0 = xp[(size_t)(2 * c) * 1024 + i] * sc[2 * c] + bi[2 * c];
      float v1 = xp[(size_t)(2 * c + 1) * 1024 + i] * sc[2 * c + 1] + bi[2 * c + 1];
      pk[c] = (unsigned int)f2bf(v0) | ((unsigned int)f2bf(v1) << 16);
    }
    uint4* dst = (uint4*)(hp + (size_t)i * 512);
    dst[0] = make_uint4(pk[0], pk[1], pk[2], pk[3]);
    dst[1] = make_uint4(pk[4], pk[5], pk[6], pk[7]);
  }
}

// ------------------------- generic NT GEMM (bf16 MFMA) ---------------------
// 128x128 tile, BK=32, 256 threads (4 waves as 2x2 of 64x64).
// A: [M][K] bf16 row-major (lda), Bt: [N][K] bf16 row-major (ldb).
// Out: [M][N] (ldo), fp32 or bf16. bias_mode: 0 none, 1 bias[m], 2 bias[n].
#define BM 128
#define BN 128
#define BKG 32

__global__ __launch_bounds__(256) void gemm_nt(
    const unsigned short* __restrict__ A, long long sAb, int lda,
    const unsigned short* __restrict__ B, long long sBb, int ldb,
    void* __restrict__ Out, long long sOb, int ldo, int out_bf16, int K,
    const float* __restrict__ bias, int bias_mode, float scale,
    const float* __restrict__ resid, long long sRb) {
  const int bz = blockIdx.z;
  const int m0 = blockIdx.y * BM, n0 = blockIdx.x * BN;
  const unsigned short* Ab = A + (size_t)bz * sAb;
  const unsigned short* Bb = B + (size_t)bz * sBb;

  __shared__ unsigned short sA[BM * BKG];
  __shared__ unsigned short sB[BN * BKG];

  const int t = threadIdx.x;
  const int wid = t >> 6, lane = t & 63;
  const int rA = t >> 2;          // staging row within 64-row half
  const int c8 = (t & 3) << 3;    // staging k-offset (ushorts)

  const unsigned short* gA = Ab + (size_t)(m0 + rA) * lda + c8;
  const unsigned short* gB = Bb + (size_t)(n0 + rA) * ldb + c8;
  char* lA = (char*)sA + (wid << 10);
  char* lB = (char*)sB + (wid << 10);

  f32x4 acc[4][4] = {};

  const int wm = wid >> 1, wn = wid & 1;
  const int fr = lane & 15;
  const int fk = (lane >> 4) << 3;
  const unsigned short* pa = sA + (wm * 64 + fr) * BKG + fk;
  const unsigned short* pb = sB + (wn * 64 + fr) * BKG + fk;

  for (int k0 = 0; k0 < K; k0 += BKG) {
    GLD16(gA + k0, lA);
    GLD16(gA + k0 + (size_t)64 * lda, lA + 4096);
    GLD16(gB + k0, lB);
    GLD16(gB + k0 + (size_t)64 * ldb, lB + 4096);
    __syncthreads();  // drains vmcnt before barrier -> tiles visible

    bf16x8 av[4], bv[4];
#pragma unroll
    for (int mf = 0; mf < 4; ++mf) av[mf] = *(const bf16x8*)(pa + mf * 16 * BKG);
#pragma unroll
    for (int nf = 0; nf < 4; ++nf) bv[nf] = *(const bf16x8*)(pb + nf * 16 * BKG);
#pragma unroll
    for (int mf = 0; mf < 4; ++mf)
#pragma unroll
      for (int nf = 0; nf < 4; ++nf)
        acc[mf][nf] = __builtin_amdgcn_mfma_f32_16x16x32_bf16(
            av[mf], bv[nf], acc[mf][nf], 0, 0, 0);
    __syncthreads();  // protect LDS before next stage
  }

  const int em = m0 + wm * 64 + (lane >> 4) * 4;
  const int en = n0 + wn * 64 + fr;
#pragma unroll
  for (int mf = 0; mf < 4; ++mf) {
#pragma unroll
    for (int nf = 0; nf < 4; ++nf) {
#pragma unroll
      for (int r = 0; r < 4; ++r) {
        const int gm = em + mf * 16 + r;
        const int gn = en + nf * 16;
        float v = acc[mf][nf][r] * scale;
        if (bias_mode == 1) v += bias[gm];
        else if (bias_mode == 2) v += bias[gn];
        if (resid) v += resid[(size_t)bz * sRb + (size_t)gm * ldo + gn];
        const size_t off = (size_t)bz * sOb + (size_t)gm * ldo + gn;
        if (out_bf16) ((unsigned short*)Out)[off] = f2bf(v);
        else ((float*)Out)[off] = v;
      }
    }
  }
}

// ------------------------- row softmax fp32 -> bf16 ------------------------
// One block per row (16*1024 rows), 1024 cols.
__global__ __launch_bounds__(256) void softmax_kernel(
    const float* __restrict__ S, unsigned short* __restrict__ W) {
  const size_t row = blockIdx.x;
  const int t = threadIdx.x;
  const int wid = t >> 6, lane = t & 63;
  const float4 v = ((const float4*)(S + row * 1024))[t];

  __shared__ float redm[4];
  __shared__ float reds[4];

  float m = fmaxf(fmaxf(v.x, v.y), fmaxf(v.z, v.w));
#pragma unroll
  for (int off = 32; off > 0; off >>= 1) m = fmaxf(m, __shfl_down(m, off));
  if (lane == 0) redm[wid] = m;
  __syncthreads();
  m = fmaxf(fmaxf(redm[0], redm[1]), fmaxf(redm[2], redm[3]));

  const float e0 = expf(v.x - m), e1 = expf(v.y - m);
  const float e2 = expf(v.z - m), e3 = expf(v.w - m);
  float s = (e0 + e1) + (e2 + e3);
#pragma unroll
  for (int off = 32; off > 0; off >>= 1) s += __shfl_down(s, off);
  if (lane == 0) reds[wid] = s;
  __syncthreads();
  const float inv = 1.f / (reds[0] + reds[1] + reds[2] + reds[3]);

  uint2 o;
  o.x = (unsigned int)f2bf(e0 * inv) | ((unsigned int)f2bf(e1 * inv) << 16);
  o.y = (unsigned int)f2bf(e2 * inv) | ((unsigned int)f2bf(e3 * inv) << 16);
  ((uint2*)(W + row * 1024))[t] = o;
}

// ---------------------------------------------------------------------------
extern "C" void kernel_launch(void* const* d_in, const int* in_sizes, int n_in,
                              void* d_out, int out_size, void* d_ws,
                              size_t ws_size, hipStream_t stream) {
  const float* x   = (const float*)d_in[0];
  const float* gsc = (const float*)d_in[1];
  const float* gbi = (const float*)d_in[2];
  const float* wq  = (const float*)d_in[3];
  const float* bq  = (const float*)d_in[4];
  const float* wk  = (const float*)d_in[5];
  const float* bk  = (const float*)d_in[6];
  const float* wv  = (const float*)d_in[7];
  const float* bv  = (const float*)d_in[8];
  const float* wp  = (const float*)d_in[9];
  const float* bp  = (const float*)d_in[10];
  float* out = (float*)d_out;

  char* ws = (char*)d_ws;
  const size_t MB = 1024ull * 1024ull;
  // 16 batches, C=512, HW=1024
  unsigned short* hT  = (unsigned short*)(ws);             // 16MB [b][i][c]; reused as attnT
  unsigned short* qT  = (unsigned short*)(ws + 16 * MB);   // 16MB [b][i][c]
  unsigned short* kT  = (unsigned short*)(ws + 32 * MB);   // 16MB [b][i][c]
  unsigned short* vB  = (unsigned short*)(ws + 48 * MB);   // 16MB [b][c][j]
  float*          S   = (float*)(ws + 64 * MB);            // 64MB [b][i][j] fp32
  unsigned short* W   = (unsigned short*)(ws + 128 * MB);  // 32MB [b][i][j] bf16
  unsigned short* wqb = (unsigned short*)(ws + 160 * MB);
  unsigned short* wkb = (unsigned short*)(ws + 160 * MB + 512 * 1024);
  unsigned short* wvb = (unsigned short*)(ws + 161 * MB);
  unsigned short* wpb = (unsigned short*)(ws + 161 * MB + 512 * 1024);

  conv_w_kernel<<<1024, 256, 0, stream>>>(wq, wk, wv, wp, wqb, wkb, wvb, wpb);
  gn_kernel<<<512, 256, 0, stream>>>(x, gsc, gbi, hT);

  const long long sHW = 1024ll * 512ll;   // per-batch stride of [1024][512]
  const long long sS  = 1024ll * 1024ll;
  const float rsK = 0.04419417382415922f; // 512^-0.5

  // q: qT[b][i][c] = sum_c' hT[i][c'] wq[c][c'] + bq[c]
  gemm_nt<<<dim3(4, 8, 16), 256, 0, stream>>>(hT, sHW, 512, wqb, 0, 512,
      qT, sHW, 512, 1, 512, bq, 2, 1.f, nullptr, 0);
  // k
  gemm_nt<<<dim3(4, 8, 16), 256, 0, stream>>>(hT, sHW, 512, wkb, 0, 512,
      kT, sHW, 512, 1, 512, bk, 2, 1.f, nullptr, 0);
  // v: v[b][c][j] = sum_c' wv[c][c'] hT[j][c'] + bv[c]
  gemm_nt<<<dim3(8, 4, 16), 256, 0, stream>>>(wvb, 0, 512, hT, sHW, 512,
      vB, sHW, 1024, 1, 512, bv, 1, 1.f, nullptr, 0);
  // scores: S[b][i][j] = (sum_c qT[i][c] kT[j][c]) * rsK
  gemm_nt<<<dim3(8, 8, 16), 256, 0, stream>>>(qT, sHW, 512, kT, sHW, 512,
      S, sS, 1024, 0, 512, nullptr, 0, rsK, nullptr, 0);
  softmax_kernel<<<16384, 256, 0, stream>>>(S, W);
  // PV: attnT[b][i][c] = sum_j W[i][j] v[c][j]   (attnT reuses hT buffer)
  gemm_nt<<<dim3(4, 8, 16), 256, 0, stream>>>(W, sS, 1024, vB, sHW, 1024,
      hT, sHW, 512, 1, 1024, nullptr, 0, 1.f, nullptr, 0);
  // proj + residual: out[b][c][i] = x + sum_c' wp[c][c'] attnT[i][c'] + bp[c]
  gemm_nt<<<dim3(8, 4, 16), 256, 0, stream>>>(wpb, 0, 512, hT, sHW, 512,
      out, sHW, 1024, 0, 512, bp, 1, 1.f, x, sHW);
}

// Round 2
// 230.525 us; speedup vs baseline: 1.1325x; 1.1325x over previous
//
#include <hip/hip_runtime.h>
#include <cstdint>
#include <cstddef>

// ---------------------------------------------------------------------------
// AttnBlock: GN -> fused(q,k) + v conv1x1 -> scaled QK^T softmax(bf16,inplace)
//            -> PV -> proj + resid.  bf16 MFMA, NT GEMMs, swizzled LDS (BK=64).
// ---------------------------------------------------------------------------

typedef __bf16 bf16x8 __attribute__((ext_vector_type(8)));
typedef float f32x4 __attribute__((ext_vector_type(4)));

typedef __attribute__((address_space(1))) const void gl_void;
typedef __attribute__((address_space(3))) void lds_void;

#define GLD16(g, l)                                                     \
  __builtin_amdgcn_global_load_lds((gl_void*)(uintptr_t)(g),            \
                                   (lds_void*)(uintptr_t)(l), 16, 0, 0)

__device__ __forceinline__ unsigned short f2bf(float f) {
  unsigned int u = __builtin_bit_cast(unsigned int, f);
  u += 0x7fffu + ((u >> 16) & 1u);  // round-to-nearest-even
  return (unsigned short)(u >> 16);
}
__device__ __forceinline__ float bf2f(unsigned int h) {
  return __builtin_bit_cast(float, h << 16);
}

// ------------------------- weights fp32 -> bf16 ----------------------------
// Builds concatenated [wq;wk] (for the fused QK GEMM), wv, wp, and bqk.
__global__ __launch_bounds__(256) void conv_w_kernel(
    const float* __restrict__ wq, const float* __restrict__ wk,
    const float* __restrict__ wv, const float* __restrict__ wp,
    const float* __restrict__ bq, const float* __restrict__ bk,
    unsigned short* __restrict__ oqk, unsigned short* __restrict__ ov,
    unsigned short* __restrict__ op, float* __restrict__ bqk) {
  int idx = blockIdx.x * 256 + threadIdx.x;  // 262144 = 512*512
  oqk[idx] = f2bf(wq[idx]);
  oqk[262144 + idx] = f2bf(wk[idx]);
  ov[idx] = f2bf(wv[idx]);
  op[idx] = f2bf(wp[idx]);
  if (idx < 1024) bqk[idx] = idx < 512 ? bq[idx] : bk[idx - 512];
}

// ------------------------- GroupNorm -> hT bf16 ----------------------------
// x: [16][512][1024] fp32. One block per (b,g). Writes hT[b][i][c] bf16.
__global__ __launch_bounds__(256) void gn_kernel(
    const float* __restrict__ x, const float* __restrict__ gsc,
    const float* __restrict__ gbi, unsigned short* __restrict__ hT) {
  const int b = blockIdx.x >> 5;
  const int g = blockIdx.x & 31;
  const int t = threadIdx.x;
  const int wid = t >> 6, lane = t & 63;
  const float* xp = x + ((size_t)(b * 512 + g * 16)) * 1024;

  float s = 0.f, s2 = 0.f;
#pragma unroll 8
  for (int e = 0; e < 64; ++e) {
    float v = xp[e * 256 + t];
    s += v;
    s2 += v * v;
  }
  __shared__ float red[2][4];
#pragma unroll
  for (int off = 32; off > 0; off >>= 1) {
    s += __shfl_down(s, off);
    s2 += __shfl_down(s2, off);
  }
  if (lane == 0) { red[0][wid] = s; red[1][wid] = s2; }
  __syncthreads();
  const float S = red[0][0] + red[0][1] + red[0][2] + red[0][3];
  const float S2 = red[1][0] + red[1][1] + red[1][2] + red[1][3];
  const float mean = S * (1.f / 16384.f);
  const float var = S2 * (1.f / 16384.f) - mean * mean;
  const float rstd = rsqrtf(var + 1e-6f);

  float sc[16], bi[16];
#pragma unroll
  for (int c = 0; c < 16; ++c) {
    sc[c] = gsc[g * 16 + c] * rstd;
    bi[c] = gbi[g * 16 + c] - mean * sc[c];
  }
  unsigned short* hp = hT + (size_t)b * 1024 * 512 + g * 16;
#pragma unroll
  for (int ii = 0; ii < 4; ++ii) {
    int i = ii * 256 + t;
    unsigned int pk[8];
#pragma unroll
    for (int c = 0; c < 8; ++c) {
      float v0 = xp[(size_t)(2 * c) * 1024 + i] * sc[2 * c] + bi[2 * c];
      float v1 = xp[(size_t)(2 * c + 1) * 1024 + i] * sc[2 * c + 1] + bi[2 * c + 1];
      pk[c] = (unsigned int)f2bf(v0) | ((unsigned int)f2bf(v1) << 16);
    }
    uint4* dst = (uint4*)(hp + (size_t)i * 512);
    dst[0] = make_uint4(pk[0], pk[1], pk[2], pk[3]);
    dst[1] = make_uint4(pk[4], pk[5], pk[6], pk[7]);
  }
}

// ------------------------- generic NT GEMM (bf16 MFMA) ---------------------
// 128x128 tile, BK=64, 256 threads (2x2 waves of 64x64).
// LDS tiles [128][64] bf16, XOR-swizzled: logical (row,chunk) stored at
// physical chunk slot (chunk ^ (row&7)); chunks are 16B (8 bf16).
// Write side stays linear for global_load_lds; the global SOURCE address is
// pre-swizzled (rule #21 / m201 pattern).
#define BM 128
#define BN 128
#define BK 64

__global__ __launch_bounds__(256) void gemm_nt(
    const unsigned short* __restrict__ A, long long sAb, int lda,
    const unsigned short* __restrict__ B, long long sBb, int ldb,
    void* __restrict__ Out, long long sOb, int ldo, int out_bf16, int K,
    const float* __restrict__ bias, int bias_mode, float scale,
    const float* __restrict__ resid, long long sRb) {
  const int bz = blockIdx.z;
  const int m0 = blockIdx.y * BM, n0 = blockIdx.x * BN;
  const unsigned short* Ab = A + (size_t)bz * sAb;
  const unsigned short* Bb = B + (size_t)bz * sBb;

  __shared__ unsigned short sA[BM * BK];  // 16KB, rows are 128B
  __shared__ unsigned short sB[BN * BK];  // 16KB

  const int t = threadIdx.x;
  const int wid = t >> 6, lane = t & 63;

  // staging: each GLD16 call deposits 4KB = 32 rows x 128B (linear in LDS).
  // thread t -> physical (row = t>>3, chunk-slot = t&7); load the global
  // chunk that BELONGS in that slot: chunk = slot ^ (row&7).
  const int srow = t >> 3;                  // 0..31 within a 32-row slab
  const int schunk = (t & 7) ^ (srow & 7);  // pre-swizzled source chunk
  const unsigned short* gA = Ab + (size_t)(m0 + srow) * lda + schunk * 8;
  const unsigned short* gB = Bb + (size_t)(n0 + srow) * ldb + schunk * 8;
  char* lA = (char*)sA + (wid << 10);
  char* lB = (char*)sB + (wid << 10);

  f32x4 acc[4][4] = {};

  const int wm = wid >> 1, wn = wid & 1;
  const int fr = lane & 15;            // fragment row (row&7 == fr&7)
  const int cb = lane >> 4;            // k-chunk base 0..3
  const int slot0 = ((cb ^ (fr & 7)) << 4);  // byte offset of kk=0 chunk
  const char* paK[2] = {
      (const char*)sA + (wm * 64 + fr) * 128 + slot0,
      (const char*)sA + (wm * 64 + fr) * 128 + (slot0 ^ 64)};
  const char* pbK[2] = {
      (const char*)sB + (wn * 64 + fr) * 128 + slot0,
      (const char*)sB + (wn * 64 + fr) * 128 + (slot0 ^ 64)};

  for (int k0 = 0; k0 < K; k0 += BK) {
#pragma unroll
    for (int c = 0; c < 4; ++c) {
      GLD16(gA + k0 + (size_t)(c * 32) * lda, lA + c * 4096);
      GLD16(gB + k0 + (size_t)(c * 32) * ldb, lB + c * 4096);
    }
    __syncthreads();  // vmcnt(0) drained before barrier

#pragma unroll
    for (int kk = 0; kk < 2; ++kk) {
      bf16x8 av[4], bv[4];
#pragma unroll
      for (int mf = 0; mf < 4; ++mf)
        av[mf] = *(const bf16x8*)(paK[kk] + mf * 2048);
#pragma unroll
      for (int nf = 0; nf < 4; ++nf)
        bv[nf] = *(const bf16x8*)(pbK[kk] + nf * 2048);
#pragma unroll
      for (int mf = 0; mf < 4; ++mf)
#pragma unroll
        for (int nf = 0; nf < 4; ++nf)
          acc[mf][nf] = __builtin_amdgcn_mfma_f32_16x16x32_bf16(
              av[mf], bv[nf], acc[mf][nf], 0, 0, 0);
    }
    __syncthreads();
  }

  const int em = m0 + wm * 64 + (lane >> 4) * 4;
  const int en = n0 + wn * 64 + fr;
#pragma unroll
  for (int mf = 0; mf < 4; ++mf) {
#pragma unroll
    for (int nf = 0; nf < 4; ++nf) {
#pragma unroll
      for (int r = 0; r < 4; ++r) {
        const int gm = em + mf * 16 + r;
        const int gn = en + nf * 16;
        float v = acc[mf][nf][r] * scale;
        if (bias_mode == 1) v += bias[gm];
        else if (bias_mode == 2) v += bias[gn];
        if (resid) v += resid[(size_t)bz * sRb + (size_t)gm * ldo + gn];
        const size_t off = (size_t)bz * sOb + (size_t)gm * ldo + gn;
        if (out_bf16) ((unsigned short*)Out)[off] = f2bf(v);
        else ((float*)Out)[off] = v;
      }
    }
  }
}

// ---------------- row softmax, bf16 in-place (1024 cols) -------------------
__global__ __launch_bounds__(256) void softmax_kernel(
    unsigned short* __restrict__ S) {
  const size_t row = blockIdx.x;
  const int t = threadIdx.x;
  const int wid = t >> 6, lane = t & 63;
  uint2 v = ((const uint2*)(S + row * 1024))[t];
  const float f0 = bf2f(v.x & 0xffffu), f1 = bf2f(v.x >> 16);
  const float f2 = bf2f(v.y & 0xffffu), f3 = bf2f(v.y >> 16);

  __shared__ float redm[4];
  __shared__ float reds[4];

  float m = fmaxf(fmaxf(f0, f1), fmaxf(f2, f3));
#pragma unroll
  for (int off = 32; off > 0; off >>= 1) m = fmaxf(m, __shfl_down(m, off));
  if (lane == 0) redm[wid] = m;
  __syncthreads();
  m = fmaxf(fmaxf(redm[0], redm[1]), fmaxf(redm[2], redm[3]));

  const float e0 = __expf(f0 - m), e1 = __expf(f1 - m);
  const float e2 = __expf(f2 - m), e3 = __expf(f3 - m);
  float s = (e0 + e1) + (e2 + e3);
#pragma unroll
  for (int off = 32; off > 0; off >>= 1) s += __shfl_down(s, off);
  if (lane == 0) reds[wid] = s;
  __syncthreads();
  const float inv = 1.f / (reds[0] + reds[1] + reds[2] + reds[3]);

  uint2 o;
  o.x = (unsigned int)f2bf(e0 * inv) | ((unsigned int)f2bf(e1 * inv) << 16);
  o.y = (unsigned int)f2bf(e2 * inv) | ((unsigned int)f2bf(e3 * inv) << 16);
  ((uint2*)(S + row * 1024))[t] = o;
}

// ---------------------------------------------------------------------------
extern "C" void kernel_launch(void* const* d_in, const int* in_sizes, int n_in,
                              void* d_out, int out_size, void* d_ws,
                              size_t ws_size, hipStream_t stream) {
  const float* x   = (const float*)d_in[0];
  const float* gsc = (const float*)d_in[1];
  const float* gbi = (const float*)d_in[2];
  const float* wq  = (const float*)d_in[3];
  const float* bq  = (const float*)d_in[4];
  const float* wk  = (const float*)d_in[5];
  const float* bk  = (const float*)d_in[6];
  const float* wv  = (const float*)d_in[7];
  const float* bv  = (const float*)d_in[8];
  const float* wp  = (const float*)d_in[9];
  const float* bp  = (const float*)d_in[10];
  float* out = (float*)d_out;

  char* ws = (char*)d_ws;
  const size_t MB = 1024ull * 1024ull;
  unsigned short* hT  = (unsigned short*)(ws);            // 16MB [b][i][c]; reused as attnT
  unsigned short* qkT = (unsigned short*)(ws + 16 * MB);  // 32MB [b][i][2c] (q||k)
  unsigned short* vB  = (unsigned short*)(ws + 48 * MB);  // 16MB [b][c][j]
  unsigned short* S   = (unsigned short*)(ws + 64 * MB);  // 32MB [b][i][j] bf16
  unsigned short* wqk = (unsigned short*)(ws + 96 * MB);  // 1MB  [1024][512]
  unsigned short* wvb = (unsigned short*)(ws + 97 * MB);
  unsigned short* wpb = (unsigned short*)(ws + 97 * MB + 512 * 1024);
  float*          bqk = (float*)(ws + 98 * MB);           // 4KB

  conv_w_kernel<<<1024, 256, 0, stream>>>(wq, wk, wv, wp, bq, bk,
                                          wqk, wvb, wpb, bqk);
  gn_kernel<<<512, 256, 0, stream>>>(x, gsc, gbi, hT);

  const long long sHW = 1024ll * 512ll;    // [1024][512] per batch
  const long long sQK = 1024ll * 1024ll;   // [1024][1024] per batch
  const float rsK = 0.04419417382415922f;  // 512^-0.5

  // fused q,k over flattened batch: qkT[i][n] = sum_c' hT[i][c'] wqk[n][c'] + bqk[n]
  gemm_nt<<<dim3(8, 128, 1), 256, 0, stream>>>(hT, 0, 512, wqk, 0, 512,
      qkT, 0, 1024, 1, 512, bqk, 2, 1.f, nullptr, 0);
  // v: vB[b][c][j] = sum_c' wv[c][c'] hT[j][c'] + bv[c]
  gemm_nt<<<dim3(8, 4, 16), 256, 0, stream>>>(wvb, 0, 512, hT, sHW, 512,
      vB, sHW, 1024, 1, 512, bv, 1, 1.f, nullptr, 0);
  // scores (bf16 out, scaled): S[b][i][j] = rsK * sum_c q[i][c] k[j][c]
  gemm_nt<<<dim3(8, 8, 16), 256, 0, stream>>>(qkT, sQK, 1024, qkT + 512, sQK, 1024,
      S, sQK, 1024, 1, 512, nullptr, 0, rsK, nullptr, 0);
  softmax_kernel<<<16384, 256, 0, stream>>>(S);
  // PV: attnT[b][i][c] = sum_j W[i][j] vB[c][j]   (attnT reuses hT)
  gemm_nt<<<dim3(4, 8, 16), 256, 0, stream>>>(S, sQK, 1024, vB, sHW, 1024,
      hT, sHW, 512, 1, 1024, nullptr, 0, 1.f, nullptr, 0);
  // proj + residual: out[b][c][i] = x + bp[c] + sum_c' wp[c][c'] attnT[i][c']
  gemm_nt<<<dim3(8, 4, 16), 256, 0, stream>>>(wpb, 0, 512, hT, sHW, 512,
      out, sHW, 1024, 0, 512, bp, 1, 1.f, x, sHW);
}

// Round 3
// 229.885 us; speedup vs baseline: 1.1356x; 1.0028x over previous
//
#include <hip/hip_runtime.h>
#include <cstdint>
#include <cstddef>

// ---------------------------------------------------------------------------
// AttnBlock: GN -> fused(q,k) + v conv1x1 -> scaled QK^T softmax(bf16,inplace)
//            -> PV -> proj + resid.  bf16 MFMA, NT GEMMs, swizzled LDS,
//            2-phase double-buffered prefetch (BK=64, 64KB LDS).
// ---------------------------------------------------------------------------

typedef __bf16 bf16x8 __attribute__((ext_vector_type(8)));
typedef float f32x4 __attribute__((ext_vector_type(4)));

typedef __attribute__((address_space(1))) const void gl_void;
typedef __attribute__((address_space(3))) void lds_void;

#define GLD16(g, l)                                                     \
  __builtin_amdgcn_global_load_lds((gl_void*)(uintptr_t)(g),            \
                                   (lds_void*)(uintptr_t)(l), 16, 0, 0)

__device__ __forceinline__ unsigned short f2bf(float f) {
  unsigned int u = __builtin_bit_cast(unsigned int, f);
  u += 0x7fffu + ((u >> 16) & 1u);  // round-to-nearest-even
  return (unsigned short)(u >> 16);
}
__device__ __forceinline__ float bf2f(unsigned int h) {
  return __builtin_bit_cast(float, h << 16);
}

// ------------------------- weights fp32 -> bf16 ----------------------------
__global__ __launch_bounds__(256) void conv_w_kernel(
    const float* __restrict__ wq, const float* __restrict__ wk,
    const float* __restrict__ wv, const float* __restrict__ wp,
    const float* __restrict__ bq, const float* __restrict__ bk,
    unsigned short* __restrict__ oqk, unsigned short* __restrict__ ov,
    unsigned short* __restrict__ op, float* __restrict__ bqk) {
  int idx = blockIdx.x * 256 + threadIdx.x;  // 262144 = 512*512
  oqk[idx] = f2bf(wq[idx]);
  oqk[262144 + idx] = f2bf(wk[idx]);
  ov[idx] = f2bf(wv[idx]);
  op[idx] = f2bf(wp[idx]);
  if (idx < 1024) bqk[idx] = idx < 512 ? bq[idx] : bk[idx - 512];
}

// ------------------------- GroupNorm -> hT bf16 ----------------------------
// x: [16][512][1024] fp32. One block per (b,g). Writes hT[b][i][c] bf16.
__global__ __launch_bounds__(256) void gn_kernel(
    const float* __restrict__ x, const float* __restrict__ gsc,
    const float* __restrict__ gbi, unsigned short* __restrict__ hT) {
  const int b = blockIdx.x >> 5;
  const int g = blockIdx.x & 31;
  const int t = threadIdx.x;
  const int wid = t >> 6, lane = t & 63;
  const float* xp = x + ((size_t)(b * 512 + g * 16)) * 1024;

  float s = 0.f, s2 = 0.f;
#pragma unroll 8
  for (int e = 0; e < 64; ++e) {
    float v = xp[e * 256 + t];
    s += v;
    s2 += v * v;
  }
  __shared__ float red[2][4];
#pragma unroll
  for (int off = 32; off > 0; off >>= 1) {
    s += __shfl_down(s, off);
    s2 += __shfl_down(s2, off);
  }
  if (lane == 0) { red[0][wid] = s; red[1][wid] = s2; }
  __syncthreads();
  const float S = red[0][0] + red[0][1] + red[0][2] + red[0][3];
  const float S2 = red[1][0] + red[1][1] + red[1][2] + red[1][3];
  const float mean = S * (1.f / 16384.f);
  const float var = S2 * (1.f / 16384.f) - mean * mean;
  const float rstd = rsqrtf(var + 1e-6f);

  float sc[16], bi[16];
#pragma unroll
  for (int c = 0; c < 16; ++c) {
    sc[c] = gsc[g * 16 + c] * rstd;
    bi[c] = gbi[g * 16 + c] - mean * sc[c];
  }
  unsigned short* hp = hT + (size_t)b * 1024 * 512 + g * 16;
#pragma unroll
  for (int ii = 0; ii < 4; ++ii) {
    int i = ii * 256 + t;
    unsigned int pk[8];
#pragma unroll
    for (int c = 0; c < 8; ++c) {
      float v0 = xp[(size_t)(2 * c) * 1024 + i] * sc[2 * c] + bi[2 * c];
      float v1 = xp[(size_t)(2 * c + 1) * 1024 + i] * sc[2 * c + 1] + bi[2 * c + 1];
      pk[c] = (unsigned int)f2bf(v0) | ((unsigned int)f2bf(v1) << 16);
    }
    uint4* dst = (uint4*)(hp + (size_t)i * 512);
    dst[0] = make_uint4(pk[0], pk[1], pk[2], pk[3]);
    dst[1] = make_uint4(pk[4], pk[5], pk[6], pk[7]);
  }
}

// ------------------------- generic NT GEMM (bf16 MFMA) ---------------------
// 128x128 tile, BK=64, 256 threads (2x2 waves of 64x64), double-buffered.
// LDS: 2 bufs x (A 16KB + B 16KB) = 64KB dynamic.
// Tiles [128][64] bf16, XOR chunk swizzle (chunk ^= row&7, 16B chunks);
// global SOURCE pre-swizzled so global_load_lds dest stays linear.
// 2-phase schedule: stage tile t+1 BEFORE computing tile t; ONE barrier/tile.
#define BM 128
#define BN 128
#define BK 64

__global__ __launch_bounds__(256) void gemm_nt(
    const unsigned short* __restrict__ A, long long sAb, int lda,
    const unsigned short* __restrict__ B, long long sBb, int ldb,
    void* __restrict__ Out, long long sOb, int ldo, int out_bf16, int K,
    const float* __restrict__ bias, int bias_mode, float scale,
    const float* __restrict__ resid, long long sRb) {
  extern __shared__ char lds[];  // [2][A:16KB | B:16KB]
  const int bz = blockIdx.z;
  const int m0 = blockIdx.y * BM, n0 = blockIdx.x * BN;
  const unsigned short* Ab = A + (size_t)bz * sAb;
  const unsigned short* Bb = B + (size_t)bz * sBb;

  const int t = threadIdx.x;
  const int wid = t >> 6, lane = t & 63;

  // staging: thread t -> physical (row=t>>3, slot=t&7); source chunk is
  // pre-swizzled (slot ^ row&7) so LDS write order stays linear.
  const int srow = t >> 3;
  const int schunk = (t & 7) ^ (srow & 7);
  const unsigned short* gA = Ab + (size_t)(m0 + srow) * lda + schunk * 8;
  const unsigned short* gB = Bb + (size_t)(n0 + srow) * ldb + schunk * 8;
  const int stgOff = wid << 10;  // wave-uniform LDS base within slab

  f32x4 acc[4][4] = {};

  const int wm = wid >> 1, wn = wid & 1;
  const int fr = lane & 15;                   // fragment row
  const int cb = lane >> 4;                   // k-chunk base 0..3
  const int slot0 = ((cb ^ (fr & 7)) << 4);   // swizzled chunk byte offset
  const int aoff = (wm * 64 + fr) * 128 + slot0;
  const int boff = 16384 + (wn * 64 + fr) * 128 + slot0;

  // prologue: stage tile 0 into buffer 0
#pragma unroll
  for (int c = 0; c < 4; ++c) {
    GLD16(gA + (size_t)(c * 32) * lda, lds + stgOff + c * 4096);
    GLD16(gB + (size_t)(c * 32) * ldb, lds + 16384 + stgOff + c * 4096);
  }
  __syncthreads();  // vmcnt(0) drained: tile 0 resident

  const int nt = K / BK;
  int bufOff = 0;
  for (int tile = 0; tile < nt; ++tile) {
    if (tile + 1 < nt) {  // stage next tile into other buffer (overlaps MFMA)
      const int k0 = (tile + 1) * BK;
      const int dst = bufOff ^ 32768;
#pragma unroll
      for (int c = 0; c < 4; ++c) {
        GLD16(gA + k0 + (size_t)(c * 32) * lda, lds + dst + stgOff + c * 4096);
        GLD16(gB + k0 + (size_t)(c * 32) * ldb,
              lds + dst + 16384 + stgOff + c * 4096);
      }
    }
    const char* pa = lds + bufOff + aoff;
    const char* pb = lds + bufOff + boff;
#pragma unroll
    for (int kk = 0; kk < 2; ++kk) {
      const int kx = kk ? 64 : 0;  // chunk slot XOR for second k-half
      bf16x8 av[4], bv[4];
#pragma unroll
      for (int mf = 0; mf < 4; ++mf)
        av[mf] = *(const bf16x8*)((const char*)((uintptr_t)pa ^ kx) + mf * 2048);
#pragma unroll
      for (int nf = 0; nf < 4; ++nf)
        bv[nf] = *(const bf16x8*)((const char*)((uintptr_t)pb ^ kx) + nf * 2048);
#pragma unroll
      for (int mf = 0; mf < 4; ++mf)
#pragma unroll
        for (int nf = 0; nf < 4; ++nf)
          acc[mf][nf] = __builtin_amdgcn_mfma_f32_16x16x32_bf16(
              av[mf], bv[nf], acc[mf][nf], 0, 0, 0);
    }
    __syncthreads();  // waits next-tile loads (issued ~550cy ago) + LDS reuse
    bufOff ^= 32768;
  }

  const int em = m0 + wm * 64 + (lane >> 4) * 4;
  const int en = n0 + wn * 64 + fr;
#pragma unroll
  for (int mf = 0; mf < 4; ++mf) {
#pragma unroll
    for (int nf = 0; nf < 4; ++nf) {
#pragma unroll
      for (int r = 0; r < 4; ++r) {
        const int gm = em + mf * 16 + r;
        const int gn = en + nf * 16;
        float v = acc[mf][nf][r] * scale;
        if (bias_mode == 1) v += bias[gm];
        else if (bias_mode == 2) v += bias[gn];
        if (resid) v += resid[(size_t)bz * sRb + (size_t)gm * ldo + gn];
        const size_t off = (size_t)bz * sOb + (size_t)gm * ldo + gn;
        if (out_bf16) ((unsigned short*)Out)[off] = f2bf(v);
        else ((float*)Out)[off] = v;
      }
    }
  }
}

// ---------------- row softmax, bf16 in-place (1024 cols) -------------------
__global__ __launch_bounds__(256) void softmax_kernel(
    unsigned short* __restrict__ S) {
  const size_t row = blockIdx.x;
  const int t = threadIdx.x;
  const int wid = t >> 6, lane = t & 63;
  uint2 v = ((const uint2*)(S + row * 1024))[t];
  const float f0 = bf2f(v.x & 0xffffu), f1 = bf2f(v.x >> 16);
  const float f2 = bf2f(v.y & 0xffffu), f3 = bf2f(v.y >> 16);

  __shared__ float redm[4];
  __shared__ float reds[4];

  float m = fmaxf(fmaxf(f0, f1), fmaxf(f2, f3));
#pragma unroll
  for (int off = 32; off > 0; off >>= 1) m = fmaxf(m, __shfl_down(m, off));
  if (lane == 0) redm[wid] = m;
  __syncthreads();
  m = fmaxf(fmaxf(redm[0], redm[1]), fmaxf(redm[2], redm[3]));

  const float e0 = __expf(f0 - m), e1 = __expf(f1 - m);
  const float e2 = __expf(f2 - m), e3 = __expf(f3 - m);
  float s = (e0 + e1) + (e2 + e3);
#pragma unroll
  for (int off = 32; off > 0; off >>= 1) s += __shfl_down(s, off);
  if (lane == 0) reds[wid] = s;
  __syncthreads();
  const float inv = 1.f / (reds[0] + reds[1] + reds[2] + reds[3]);

  uint2 o;
  o.x = (unsigned int)f2bf(e0 * inv) | ((unsigned int)f2bf(e1 * inv) << 16);
  o.y = (unsigned int)f2bf(e2 * inv) | ((unsigned int)f2bf(e3 * inv) << 16);
  ((uint2*)(S + row * 1024))[t] = o;
}

// ---------------------------------------------------------------------------
extern "C" void kernel_launch(void* const* d_in, const int* in_sizes, int n_in,
                              void* d_out, int out_size, void* d_ws,
                              size_t ws_size, hipStream_t stream) {
  const float* x   = (const float*)d_in[0];
  const float* gsc = (const float*)d_in[1];
  const float* gbi = (const float*)d_in[2];
  const float* wq  = (const float*)d_in[3];
  const float* bq  = (const float*)d_in[4];
  const float* wk  = (const float*)d_in[5];
  const float* bk  = (const float*)d_in[6];
  const float* wv  = (const float*)d_in[7];
  const float* bv  = (const float*)d_in[8];
  const float* wp  = (const float*)d_in[9];
  const float* bp  = (const float*)d_in[10];
  float* out = (float*)d_out;

  char* ws = (char*)d_ws;
  const size_t MB = 1024ull * 1024ull;
  unsigned short* hT  = (unsigned short*)(ws);            // 16MB [b][i][c]; reused as attnT
  unsigned short* qkT = (unsigned short*)(ws + 16 * MB);  // 32MB [b][i][2c] (q||k)
  unsigned short* vB  = (unsigned short*)(ws + 48 * MB);  // 16MB [b][c][j]
  unsigned short* S   = (unsigned short*)(ws + 64 * MB);  // 32MB [b][i][j] bf16
  unsigned short* wqk = (unsigned short*)(ws + 96 * MB);  // 1MB  [1024][512]
  unsigned short* wvb = (unsigned short*)(ws + 97 * MB);
  unsigned short* wpb = (unsigned short*)(ws + 97 * MB + 512 * 1024);
  float*          bqk = (float*)(ws + 98 * MB);           // 4KB

  conv_w_kernel<<<1024, 256, 0, stream>>>(wq, wk, wv, wp, bq, bk,
                                          wqk, wvb, wpb, bqk);
  gn_kernel<<<512, 256, 0, stream>>>(x, gsc, gbi, hT);

  const long long sHW = 1024ll * 512ll;    // [1024][512] per batch
  const long long sQK = 1024ll * 1024ll;   // [1024][1024] per batch
  const float rsK = 0.04419417382415922f;  // 512^-0.5
  const int LDSB = 65536;

  // fused q,k over flattened batch: qkT[i][n] = sum_c' hT[i][c'] wqk[n][c'] + bqk[n]
  gemm_nt<<<dim3(8, 128, 1), 256, LDSB, stream>>>(hT, 0, 512, wqk, 0, 512,
      qkT, 0, 1024, 1, 512, bqk, 2, 1.f, nullptr, 0);
  // v: vB[b][c][j] = sum_c' wv[c][c'] hT[j][c'] + bv[c]
  gemm_nt<<<dim3(8, 4, 16), 256, LDSB, stream>>>(wvb, 0, 512, hT, sHW, 512,
      vB, sHW, 1024, 1, 512, bv, 1, 1.f, nullptr, 0);
  // scores (bf16 out, scaled): S[b][i][j] = rsK * sum_c q[i][c] k[j][c]
  gemm_nt<<<dim3(8, 8, 16), 256, LDSB, stream>>>(qkT, sQK, 1024, qkT + 512, sQK, 1024,
      S, sQK, 1024, 1, 512, nullptr, 0, rsK, nullptr, 0);
  softmax_kernel<<<16384, 256, 0, stream>>>(S);
  // PV: attnT[b][i][c] = sum_j W[i][j] vB[c][j]   (attnT reuses hT)
  gemm_nt<<<dim3(4, 8, 16), 256, LDSB, stream>>>(S, sQK, 1024, vB, sHW, 1024,
      hT, sHW, 512, 1, 1024, nullptr, 0, 1.f, nullptr, 0);
  // proj + residual: out[b][c][i] = x + bp[c] + sum_c' wp[c][c'] attnT[i][c']
  gemm_nt<<<dim3(8, 4, 16), 256, LDSB, stream>>>(wpb, 0, 512, hT, sHW, 512,
      out, sHW, 1024, 0, 512, bp, 1, 1.f, x, sHW);
}

// Round 4
// 216.603 us; speedup vs baseline: 1.2053x; 1.0613x over previous
//
#include <hip/hip_runtime.h>
#include <cstdint>
#include <cstddef>

// ---------------------------------------------------------------------------
// AttnBlock: GN -> fused(q,k) + v conv1x1 -> scaled QK^T softmax(bf16,inplace)
//            -> PV -> proj + resid.
// GEMM engine: 256x128 tile, 8 waves (4x2 of 64x64), BK=64, TRIPLE-buffered
// LDS (144KB), counted vmcnt(6), one raw s_barrier per K-tile, XCD remap.
// ---------------------------------------------------------------------------

typedef __bf16 bf16x8 __attribute__((ext_vector_type(8)));
typedef float f32x4 __attribute__((ext_vector_type(4)));

typedef __attribute__((address_space(1))) const void gl_void;
typedef __attribute__((address_space(3))) void lds_void;

#define GLD16(g, l)                                                     \
  __builtin_amdgcn_global_load_lds((gl_void*)(uintptr_t)(g),            \
                                   (lds_void*)(uintptr_t)(l), 16, 0, 0)

__device__ __forceinline__ unsigned short f2bf(float f) {
  unsigned int u = __builtin_bit_cast(unsigned int, f);
  u += 0x7fffu + ((u >> 16) & 1u);  // round-to-nearest-even
  return (unsigned short)(u >> 16);
}
__device__ __forceinline__ float bf2f(unsigned int h) {
  return __builtin_bit_cast(float, h << 16);
}

// ------------------------- weights fp32 -> bf16 ----------------------------
__global__ __launch_bounds__(256) void conv_w_kernel(
    const float* __restrict__ wq, const float* __restrict__ wk,
    const float* __restrict__ wv, const float* __restrict__ wp,
    const float* __restrict__ bq, const float* __restrict__ bk,
    unsigned short* __restrict__ oqk, unsigned short* __restrict__ ov,
    unsigned short* __restrict__ op, float* __restrict__ bqk) {
  int idx = blockIdx.x * 256 + threadIdx.x;  // 262144 = 512*512
  oqk[idx] = f2bf(wq[idx]);
  oqk[262144 + idx] = f2bf(wk[idx]);
  ov[idx] = f2bf(wv[idx]);
  op[idx] = f2bf(wp[idx]);
  if (idx < 1024) bqk[idx] = idx < 512 ? bq[idx] : bk[idx - 512];
}

// ------------------------- GroupNorm -> hT bf16 ----------------------------
__global__ __launch_bounds__(256) void gn_kernel(
    const float* __restrict__ x, const float* __restrict__ gsc,
    const float* __restrict__ gbi, unsigned short* __restrict__ hT) {
  const int b = blockIdx.x >> 5;
  const int g = blockIdx.x & 31;
  const int t = threadIdx.x;
  const int wid = t >> 6, lane = t & 63;
  const float* xp = x + ((size_t)(b * 512 + g * 16)) * 1024;

  float s = 0.f, s2 = 0.f;
#pragma unroll 8
  for (int e = 0; e < 64; ++e) {
    float v = xp[e * 256 + t];
    s += v;
    s2 += v * v;
  }
  __shared__ float red[2][4];
#pragma unroll
  for (int off = 32; off > 0; off >>= 1) {
    s += __shfl_down(s, off);
    s2 += __shfl_down(s2, off);
  }
  if (lane == 0) { red[0][wid] = s; red[1][wid] = s2; }
  __syncthreads();
  const float S = red[0][0] + red[0][1] + red[0][2] + red[0][3];
  const float S2 = red[1][0] + red[1][1] + red[1][2] + red[1][3];
  const float mean = S * (1.f / 16384.f);
  const float var = S2 * (1.f / 16384.f) - mean * mean;
  const float rstd = rsqrtf(var + 1e-6f);

  float sc[16], bi[16];
#pragma unroll
  for (int c = 0; c < 16; ++c) {
    sc[c] = gsc[g * 16 + c] * rstd;
    bi[c] = gbi[g * 16 + c] - mean * sc[c];
  }
  unsigned short* hp = hT + (size_t)b * 1024 * 512 + g * 16;
#pragma unroll
  for (int ii = 0; ii < 4; ++ii) {
    int i = ii * 256 + t;
    unsigned int pk[8];
#pragma unroll
    for (int c = 0; c < 8; ++c) {
      float v0 = xp[(size_t)(2 * c) * 1024 + i] * sc[2 * c] + bi[2 * c];
      float v1 = xp[(size_t)(2 * c + 1) * 1024 + i] * sc[2 * c + 1] + bi[2 * c + 1];
      pk[c] = (unsigned int)f2bf(v0) | ((unsigned int)f2bf(v1) << 16);
    }
    uint4* dst = (uint4*)(hp + (size_t)i * 512);
    dst[0] = make_uint4(pk[0], pk[1], pk[2], pk[3]);
    dst[1] = make_uint4(pk[4], pk[5], pk[6], pk[7]);
  }
}

// ------------------------- NT GEMM engine ----------------------------------
// D[m][n] = scale * sum_k A[m][k] * Bt[n][k]  (+bias, +resid)
// M flattened over batch when applicable; bt_batch: Bt += (m0>>10)*sBb.
// col_split: out col gn decomposes as (b=gn>>10, j=gn&1023):
//            off = b*sOb + gm*ldo + j   (also used for resid)
#define BMg 256
#define BNg 128
#define BKg 64
#define BUF 49152  // per-buffer: A 32KB + B 16KB

__global__ __launch_bounds__(512, 2) void gemm_nt(
    const unsigned short* __restrict__ A, int lda,
    const unsigned short* __restrict__ B, int ldb, long long sBb, int bt_batch,
    void* __restrict__ Out, int ldo, long long sOb, int out_bf16, int col_split,
    int K, const float* __restrict__ bias, int bias_mode, float scale,
    const float* __restrict__ resid) {
  __shared__ char lds[3 * BUF];  // 144KB

  // XCD-chunked tile remap (nwg % 8 == 0 for all our grids)
  const int nx = gridDim.x;
  const int nwg = nx * gridDim.y;
  const int cpx = nwg >> 3;
  int id = blockIdx.y * nx + blockIdx.x;
  id = (id & 7) * cpx + (id >> 3);
  const int bx = id % nx, by = id / nx;
  const int m0 = by * BMg, n0 = bx * BNg;

  const unsigned short* Ab = A + (size_t)m0 * lda;
  const unsigned short* Bb = B + (bt_batch ? (size_t)(m0 >> 10) * sBb : 0);

  const int t = threadIdx.x;
  const int wid = t >> 6, lane = t & 63;

  // staging map: thread t -> (row = t>>3 within 64-row slab, slot = t&7);
  // source chunk pre-swizzled (slot ^ row&7) so LDS dest stays linear.
  const int srow = t >> 3;
  const int schunk = ((t & 7) ^ (srow & 7)) * 8;
  const unsigned short* gA = Ab + (size_t)srow * lda + schunk;
  const unsigned short* gB = Bb + (size_t)(n0 + srow) * ldb + schunk;
  const int stgO = wid << 10;  // wave-uniform LDS sub-base

  f32x4 acc[4][4] = {};
  const int wm = wid >> 1, wn = wid & 1;       // 4x2 waves of 64x64
  const int fr = lane & 15;
  const int slot0 = (((lane >> 4) ^ (fr & 7)) << 4);
  const int aoff = (wm * 64 + fr) * 128 + slot0;
  const int boff = 32768 + (wn * 64 + fr) * 128 + slot0;

  const int nt = K / BKg;

#define STAGE(kt, bo)                                                        \
  do {                                                                       \
    const size_t ko_ = (size_t)(kt)*BKg;                                     \
    _Pragma("unroll") for (int c = 0; c < 4; ++c)                            \
        GLD16(gA + (size_t)(c * 64) * lda + ko_,                             \
              lds + (bo) + c * 8192 + stgO);                                 \
    _Pragma("unroll") for (int c = 0; c < 2; ++c)                            \
        GLD16(gB + (size_t)(c * 64) * ldb + ko_,                             \
              lds + (bo) + 32768 + c * 8192 + stgO);                         \
  } while (0)

  STAGE(0, 0);
  STAGE(1, BUF);
  int cur = 0, stg = 2 * BUF;

  for (int tt = 0; tt < nt; ++tt) {
    if (tt + 1 < nt) asm volatile("s_waitcnt vmcnt(6)" ::: "memory");
    else             asm volatile("s_waitcnt vmcnt(0)" ::: "memory");
    __builtin_amdgcn_s_barrier();          // all waves' tile-tt loads landed
    if (tt + 2 < nt) STAGE(tt + 2, stg);   // deep prefetch, stays in flight
    const char* pa = lds + cur + aoff;
    const char* pb = lds + cur + boff;
#pragma unroll
    for (int kk = 0; kk < 2; ++kk) {
      const int kx = kk ? 64 : 0;
      bf16x8 av[4], bv[4];
#pragma unroll
      for (int mf = 0; mf < 4; ++mf)
        av[mf] = *(const bf16x8*)((const char*)((uintptr_t)pa ^ kx) + mf * 2048);
#pragma unroll
      for (int nf = 0; nf < 4; ++nf)
        bv[nf] = *(const bf16x8*)((const char*)((uintptr_t)pb ^ kx) + nf * 2048);
      __builtin_amdgcn_s_setprio(1);
#pragma unroll
      for (int mf = 0; mf < 4; ++mf)
#pragma unroll
        for (int nf = 0; nf < 4; ++nf)
          acc[mf][nf] = __builtin_amdgcn_mfma_f32_16x16x32_bf16(
              av[mf], bv[nf], acc[mf][nf], 0, 0, 0);
      __builtin_amdgcn_s_setprio(0);
    }
    // rotate: next stage target is the buffer we just computed from
    int nxt = cur + BUF;
    if (nxt == 3 * BUF) nxt = 0;
    stg = cur;
    cur = nxt;
  }
#undef STAGE

  const int em = m0 + wm * 64 + (lane >> 4) * 4;
  const int en = n0 + wn * 64 + fr;
#pragma unroll
  for (int mf = 0; mf < 4; ++mf) {
#pragma unroll
    for (int nf = 0; nf < 4; ++nf) {
#pragma unroll
      for (int r = 0; r < 4; ++r) {
        const int gm = em + mf * 16 + r;
        const int gn = en + nf * 16;
        float v = acc[mf][nf][r] * scale;
        if (bias_mode == 1) v += bias[gm];
        else if (bias_mode == 2) v += bias[gn];
        size_t off;
        if (col_split)
          off = (size_t)(gn >> 10) * sOb + (size_t)gm * ldo + (gn & 1023);
        else
          off = (size_t)gm * ldo + gn;
        if (resid) v += resid[off];
        if (out_bf16) ((unsigned short*)Out)[off] = f2bf(v);
        else ((float*)Out)[off] = v;
      }
    }
  }
}

// ---------------- row softmax, bf16 in-place (1024 cols) -------------------
__global__ __launch_bounds__(256) void softmax_kernel(
    unsigned short* __restrict__ S) {
  const size_t row = blockIdx.x;
  const int t = threadIdx.x;
  const int wid = t >> 6, lane = t & 63;
  uint2 v = ((const uint2*)(S + row * 1024))[t];
  const float f0 = bf2f(v.x & 0xffffu), f1 = bf2f(v.x >> 16);
  const float f2 = bf2f(v.y & 0xffffu), f3 = bf2f(v.y >> 16);

  __shared__ float redm[4];
  __shared__ float reds[4];

  float m = fmaxf(fmaxf(f0, f1), fmaxf(f2, f3));
#pragma unroll
  for (int off = 32; off > 0; off >>= 1) m = fmaxf(m, __shfl_down(m, off));
  if (lane == 0) redm[wid] = m;
  __syncthreads();
  m = fmaxf(fmaxf(redm[0], redm[1]), fmaxf(redm[2], redm[3]));

  const float e0 = __expf(f0 - m), e1 = __expf(f1 - m);
  const float e2 = __expf(f2 - m), e3 = __expf(f3 - m);
  float s = (e0 + e1) + (e2 + e3);
#pragma unroll
  for (int off = 32; off > 0; off >>= 1) s += __shfl_down(s, off);
  if (lane == 0) reds[wid] = s;
  __syncthreads();
  const float inv = 1.f / (reds[0] + reds[1] + reds[2] + reds[3]);

  uint2 o;
  o.x = (unsigned int)f2bf(e0 * inv) | ((unsigned int)f2bf(e1 * inv) << 16);
  o.y = (unsigned int)f2bf(e2 * inv) | ((unsigned int)f2bf(e3 * inv) << 16);
  ((uint2*)(S + row * 1024))[t] = o;
}

// ---------------------------------------------------------------------------
extern "C" void kernel_launch(void* const* d_in, const int* in_sizes, int n_in,
                              void* d_out, int out_size, void* d_ws,
                              size_t ws_size, hipStream_t stream) {
  const float* x   = (const float*)d_in[0];
  const float* gsc = (const float*)d_in[1];
  const float* gbi = (const float*)d_in[2];
  const float* wq  = (const float*)d_in[3];
  const float* bq  = (const float*)d_in[4];
  const float* wk  = (const float*)d_in[5];
  const float* bk  = (const float*)d_in[6];
  const float* wv  = (const float*)d_in[7];
  const float* bv  = (const float*)d_in[8];
  const float* wp  = (const float*)d_in[9];
  const float* bp  = (const float*)d_in[10];
  float* out = (float*)d_out;

  char* ws = (char*)d_ws;
  const size_t MB = 1024ull * 1024ull;
  unsigned short* hT  = (unsigned short*)(ws);            // 16MB [16384][512]; reused as attnT
  unsigned short* qkT = (unsigned short*)(ws + 16 * MB);  // 32MB [16384][1024] (q||k)
  unsigned short* vB  = (unsigned short*)(ws + 48 * MB);  // 16MB [b][512][1024]
  unsigned short* S   = (unsigned short*)(ws + 64 * MB);  // 32MB [16384][1024]
  unsigned short* wqk = (unsigned short*)(ws + 96 * MB);  // 1MB  [1024][512]
  unsigned short* wvb = (unsigned short*)(ws + 97 * MB);
  unsigned short* wpb = (unsigned short*)(ws + 97 * MB + 512 * 1024);
  float*          bqk = (float*)(ws + 98 * MB);           // 4KB

  conv_w_kernel<<<1024, 256, 0, stream>>>(wq, wk, wv, wp, bq, bk,
                                          wqk, wvb, wpb, bqk);
  gn_kernel<<<512, 256, 0, stream>>>(x, gsc, gbi, hT);

  const float rsK = 0.04419417382415922f;  // 512^-0.5

  // qk fused: qkT[m][n] = sum_c hT[m][c] wqk[n][c] + bqk[n]
  gemm_nt<<<dim3(8, 64), 512, 0, stream>>>(hT, 512, wqk, 512, 0, 0,
      qkT, 1024, 0, 1, 0, 512, bqk, 2, 1.f, nullptr);
  // v (N flat over (b,j)): vB[b][c][j] = sum_c' wv[c][c'] hT[b*1024+j][c'] + bv[c]
  gemm_nt<<<dim3(128, 2), 512, 0, stream>>>(wvb, 512, hT, 512, 0, 0,
      vB, 1024, 524288, 1, 1, 512, bv, 1, 1.f, nullptr);
  // scores: S[m=(b,i)][j] = rsK * sum_c q[m][c] k[b*1024+j][c]
  gemm_nt<<<dim3(8, 64), 512, 0, stream>>>(qkT, 1024, qkT + 512, 1024, 1048576, 1,
      S, 1024, 0, 1, 0, 512, nullptr, 0, rsK, nullptr);
  softmax_kernel<<<16384, 256, 0, stream>>>(S);
  // PV: attnT[m=(b,i)][c] = sum_j S[m][j] vB[b][c][j]   (attnT reuses hT)
  gemm_nt<<<dim3(4, 64), 512, 0, stream>>>(S, 1024, vB, 1024, 524288, 1,
      hT, 512, 0, 1, 0, 1024, nullptr, 0, 1.f, nullptr);
  // proj + resid (N flat): out[b][c][i] = x + bp[c] + sum_c' wp[c][c'] attnT[b*1024+i][c']
  gemm_nt<<<dim3(128, 2), 512, 0, stream>>>(wpb, 512, hT, 512, 0, 0,
      out, 1024, 524288, 0, 1, 512, bp, 1, 1.f, x);
}

// Round 5
// 211.128 us; speedup vs baseline: 1.2365x; 1.0259x over previous
//
#include <hip/hip_runtime.h>
#include <cstdint>
#include <cstddef>

// ---------------------------------------------------------------------------
// AttnBlock: [gn+wconv] -> [qk|v GEMM hetero] -> [scores] -> [softmax]
//            -> [PV] -> [proj+resid].  bf16 MFMA NT GEMMs.
// Engine: BM x 128 tiles, 4 waves, wave-tile (BM/2)x64, BK=64, single-buffer
// LDS, 2-barrier loop, chunk-swizzled LDS, XCD-chunked remap.
// ---------------------------------------------------------------------------

typedef __bf16 bf16x8 __attribute__((ext_vector_type(8)));
typedef float f32x4 __attribute__((ext_vector_type(4)));

typedef __attribute__((address_space(1))) const void gl_void;
typedef __attribute__((address_space(3))) void lds_void;

#define GLD16(g, l)                                                     \
  __builtin_amdgcn_global_load_lds((gl_void*)(uintptr_t)(g),            \
                                   (lds_void*)(uintptr_t)(l), 16, 0, 0)

__device__ __forceinline__ unsigned short f2bf(float f) {
  unsigned int u = __builtin_bit_cast(unsigned int, f);
  u += 0x7fffu + ((u >> 16) & 1u);  // round-to-nearest-even
  return (unsigned short)(u >> 16);
}
__device__ __forceinline__ float bf2f(unsigned int h) {
  return __builtin_bit_cast(float, h << 16);
}

// ---------------- prep: GroupNorm (blocks 0-511) + weights (512-1535) ------
__global__ __launch_bounds__(256) void prep_kernel(
    const float* __restrict__ x, const float* __restrict__ gsc,
    const float* __restrict__ gbi, unsigned short* __restrict__ hT,
    const float* __restrict__ wq, const float* __restrict__ wk,
    const float* __restrict__ wv, const float* __restrict__ wp,
    const float* __restrict__ bq, const float* __restrict__ bk,
    unsigned short* __restrict__ oqk, unsigned short* __restrict__ ov,
    unsigned short* __restrict__ op, float* __restrict__ bqk) {
  const int t = threadIdx.x;
  if (blockIdx.x >= 512) {  // ---- weight fp32 -> bf16 ----
    int idx = (blockIdx.x - 512) * 256 + t;  // 262144 = 512*512
    oqk[idx] = f2bf(wq[idx]);
    oqk[262144 + idx] = f2bf(wk[idx]);
    ov[idx] = f2bf(wv[idx]);
    op[idx] = f2bf(wp[idx]);
    if (idx < 1024) bqk[idx] = idx < 512 ? bq[idx] : bk[idx - 512];
    return;
  }
  // ---- GroupNorm -> hT[b][i][c] bf16 (transposed) ----
  const int b = blockIdx.x >> 5;
  const int g = blockIdx.x & 31;
  const int wid = t >> 6, lane = t & 63;
  const float* xp = x + ((size_t)(b * 512 + g * 16)) * 1024;

  float s = 0.f, s2 = 0.f;
#pragma unroll 8
  for (int e = 0; e < 64; ++e) {
    float v = xp[e * 256 + t];
    s += v;
    s2 += v * v;
  }
  __shared__ float red[2][4];
#pragma unroll
  for (int off = 32; off > 0; off >>= 1) {
    s += __shfl_down(s, off);
    s2 += __shfl_down(s2, off);
  }
  if (lane == 0) { red[0][wid] = s; red[1][wid] = s2; }
  __syncthreads();
  const float S = red[0][0] + red[0][1] + red[0][2] + red[0][3];
  const float S2 = red[1][0] + red[1][1] + red[1][2] + red[1][3];
  const float mean = S * (1.f / 16384.f);
  const float var = S2 * (1.f / 16384.f) - mean * mean;
  const float rstd = rsqrtf(var + 1e-6f);

  float sc[16], bi[16];
#pragma unroll
  for (int c = 0; c < 16; ++c) {
    sc[c] = gsc[g * 16 + c] * rstd;
    bi[c] = gbi[g * 16 + c] - mean * sc[c];
  }
  unsigned short* hp = hT + (size_t)b * 1024 * 512 + g * 16;
#pragma unroll
  for (int ii = 0; ii < 4; ++ii) {
    int i = ii * 256 + t;
    unsigned int pk[8];
#pragma unroll
    for (int c = 0; c < 8; ++c) {
      float v0 = xp[(size_t)(2 * c) * 1024 + i] * sc[2 * c] + bi[2 * c];
      float v1 = xp[(size_t)(2 * c + 1) * 1024 + i] * sc[2 * c + 1] + bi[2 * c + 1];
      pk[c] = (unsigned int)f2bf(v0) | ((unsigned int)f2bf(v1) << 16);
    }
    uint4* dst = (uint4*)(hp + (size_t)i * 512);
    dst[0] = make_uint4(pk[0], pk[1], pk[2], pk[3]);
    dst[1] = make_uint4(pk[4], pk[5], pk[6], pk[7]);
  }
}

// ------------------------- NT GEMM engine ----------------------------------
// D[m][n] = scale * sum_k A[m][k]*Bt[n][k] (+bias, +resid).
// BM x 128 block, 4 waves (2x2), wave-tile (BM/2)x64, BK=64.
// LDS single-buffered: A BM*128B, B 16KB; chunk-swizzle (slot = chunk^(row&7)).
struct GArgs {
  const unsigned short *A, *B;
  void* Out;
  const float *bias, *resid;
  long long sBb, sOb;
  int lda, ldb, ldo, bt, obf, csplit, K, bmode, nx, nwg;
  float scale;
};

template <int BM>
__global__ __launch_bounds__(256, (BM == 256 ? 2 : 3)) void gemm_nt(
    GArgs g0, GArgs g1, int split) {
  constexpr int MF = BM / 32;      // m-frags per wave (8 / 4)
  constexpr int WMS = BM / 2;      // wave m-span (128 / 64)
  constexpr int ASLABS = BM / 32;  // staging slabs for A (8 / 4)
  constexpr int BOFF = BM * 128;   // byte offset of B region in LDS
  __shared__ char lds[BM * 128 + 16384];

  const bool r1 = (int)blockIdx.x >= split;
  const GArgs g = r1 ? g1 : g0;
  const int lid = blockIdx.x - (r1 ? split : 0);

  // XCD-chunked remap within role (nwg % 8 == 0 for all our grids)
  const int cpx = g.nwg >> 3;
  const int rid = (lid & 7) * cpx + (lid >> 3);
  const int bx = rid % g.nx, by = rid / g.nx;
  const int m0 = by * BM, n0 = bx * 128;

  const int t = threadIdx.x;
  const int wid = t >> 6, lane = t & 63;
  const int srow = t >> 3;                        // 32-row slab row
  const int schunk = ((t & 7) ^ (srow & 7)) * 8;  // pre-swizzled src chunk
  const unsigned short* gA = g.A + (size_t)(m0 + srow) * g.lda + schunk;
  const unsigned short* gB = g.B + (g.bt ? (size_t)(m0 >> 10) * g.sBb : 0) +
                             (size_t)(n0 + srow) * g.ldb + schunk;
  const int stgO = wid << 10;  // wave-uniform 1KB sub-slab

  f32x4 acc[MF][4] = {};
  const int wm = wid >> 1, wn = wid & 1;
  const int fr = lane & 15;
  const int slot0 = (((lane >> 4) ^ (fr & 7)) << 4);
  const int aoff = (wm * WMS + fr) * 128 + slot0;
  const int boff = BOFF + (wn * 64 + fr) * 128 + slot0;

  const int nt = g.K >> 6;
  for (int tt = 0; tt < nt; ++tt) {
    const size_t ko = (size_t)tt * 64;
#pragma unroll
    for (int c = 0; c < ASLABS; ++c)
      GLD16(gA + ko + (size_t)(c * 32) * g.lda, lds + c * 4096 + stgO);
#pragma unroll
    for (int c = 0; c < 4; ++c)
      GLD16(gB + ko + (size_t)(c * 32) * g.ldb, lds + BOFF + c * 4096 + stgO);
    __syncthreads();  // drains vmcnt -> tile visible to all waves
#pragma unroll
    for (int kk = 0; kk < 2; ++kk) {
      const int kx = kk ? 64 : 0;  // second k-half: chunk slot ^= 4
      bf16x8 av[MF], bv[4];
#pragma unroll
      for (int mf = 0; mf < MF; ++mf)
        av[mf] = *(const bf16x8*)(lds + ((aoff + mf * 2048) ^ kx));
#pragma unroll
      for (int nf = 0; nf < 4; ++nf)
        bv[nf] = *(const bf16x8*)(lds + ((boff + nf * 2048) ^ kx));
      __builtin_amdgcn_s_setprio(1);
#pragma unroll
      for (int mf = 0; mf < MF; ++mf)
#pragma unroll
        for (int nf = 0; nf < 4; ++nf)
          acc[mf][nf] = __builtin_amdgcn_mfma_f32_16x16x32_bf16(
              av[mf], bv[nf], acc[mf][nf], 0, 0, 0);
      __builtin_amdgcn_s_setprio(0);
    }
    __syncthreads();  // protect LDS before next stage
  }

  const int em = m0 + wm * WMS + (lane >> 4) * 4;
  const int en = n0 + wn * 64 + fr;
#pragma unroll
  for (int mf = 0; mf < MF; ++mf) {
#pragma unroll
    for (int nf = 0; nf < 4; ++nf) {
#pragma unroll
      for (int r = 0; r < 4; ++r) {
        const int gm = em + mf * 16 + r;
        const int gn = en + nf * 16;
        float v = acc[mf][nf][r] * g.scale;
        if (g.bmode == 1) v += g.bias[gm];
        else if (g.bmode == 2) v += g.bias[gn];
        size_t off;
        if (g.csplit)
          off = (size_t)(gn >> 10) * g.sOb + (size_t)gm * g.ldo + (gn & 1023);
        else
          off = (size_t)gm * g.ldo + gn;
        if (g.resid) v += g.resid[off];
        if (g.obf) ((unsigned short*)g.Out)[off] = f2bf(v);
        else ((float*)g.Out)[off] = v;
      }
    }
  }
}

// ------------- row softmax, bf16 in-place, max-free (|S|<~1.5) -------------
__global__ __launch_bounds__(256) void softmax_kernel(
    unsigned short* __restrict__ S) {
  const size_t row = blockIdx.x;
  const int t = threadIdx.x;
  const int wid = t >> 6, lane = t & 63;
  uint2 v = ((const uint2*)(S + row * 1024))[t];
  const float e0 = __expf(bf2f(v.x & 0xffffu));
  const float e1 = __expf(bf2f(v.x >> 16));
  const float e2 = __expf(bf2f(v.y & 0xffffu));
  const float e3 = __expf(bf2f(v.y >> 16));

  __shared__ float reds[4];
  float s = (e0 + e1) + (e2 + e3);
#pragma unroll
  for (int off = 32; off > 0; off >>= 1) s += __shfl_down(s, off);
  if (lane == 0) reds[wid] = s;
  __syncthreads();
  const float inv = 1.f / (reds[0] + reds[1] + reds[2] + reds[3]);

  uint2 o;
  o.x = (unsigned int)f2bf(e0 * inv) | ((unsigned int)f2bf(e1 * inv) << 16);
  o.y = (unsigned int)f2bf(e2 * inv) | ((unsigned int)f2bf(e3 * inv) << 16);
  ((uint2*)(S + row * 1024))[t] = o;
}

// ---------------------------------------------------------------------------
extern "C" void kernel_launch(void* const* d_in, const int* in_sizes, int n_in,
                              void* d_out, int out_size, void* d_ws,
                              size_t ws_size, hipStream_t stream) {
  const float* x   = (const float*)d_in[0];
  const float* gsc = (const float*)d_in[1];
  const float* gbi = (const float*)d_in[2];
  const float* wq  = (const float*)d_in[3];
  const float* bq  = (const float*)d_in[4];
  const float* wk  = (const float*)d_in[5];
  const float* bk  = (const float*)d_in[6];
  const float* wv  = (const float*)d_in[7];
  const float* bv  = (const float*)d_in[8];
  const float* wp  = (const float*)d_in[9];
  const float* bp  = (const float*)d_in[10];
  float* out = (float*)d_out;

  char* ws = (char*)d_ws;
  const size_t MB = 1024ull * 1024ull;
  unsigned short* hT  = (unsigned short*)(ws);            // 16MB [16384][512]; reused attnT
  unsigned short* qkT = (unsigned short*)(ws + 16 * MB);  // 32MB [16384][1024] (q||k)
  unsigned short* vB  = (unsigned short*)(ws + 48 * MB);  // 16MB [b][512][1024]
  unsigned short* S   = (unsigned short*)(ws + 64 * MB);  // 32MB [16384][1024]
  unsigned short* wqk = (unsigned short*)(ws + 96 * MB);  // 1MB [1024][512]
  unsigned short* wvb = (unsigned short*)(ws + 97 * MB);
  unsigned short* wpb = (unsigned short*)(ws + 97 * MB + 512 * 1024);
  float*          bqk = (float*)(ws + 98 * MB);           // 4KB

  prep_kernel<<<1536, 256, 0, stream>>>(x, gsc, gbi, hT, wq, wk, wv, wp,
                                        bq, bk, wqk, wvb, wpb, bqk);

  const float rsK = 0.04419417382415922f;  // 512^-0.5
  GArgs qk{hT, wqk, qkT, bqk, nullptr, 0, 0,
           512, 512, 1024, 0, 1, 0, 512, 2, 8, 512, 1.f};
  GArgs vA{wvb, hT, vB, bv, nullptr, 0, 524288,
           512, 512, 1024, 0, 1, 1, 512, 1, 128, 256, 1.f};
  GArgs sc{qkT, qkT + 512, S, nullptr, nullptr, 1048576, 0,
           1024, 1024, 1024, 1, 1, 0, 512, 0, 8, 512, rsK};
  GArgs pv{S, vB, hT, nullptr, nullptr, 524288, 0,
           1024, 1024, 512, 1, 1, 0, 1024, 0, 4, 512, 1.f};
  GArgs pj{wpb, hT, out, bp, x, 0, 524288,
           512, 512, 1024, 0, 0, 1, 512, 1, 128, 512, 1.f};

  // qk (512 blocks, BM256) + v (256 blocks, BM256) heterogeneous
  gemm_nt<256><<<768, 256, 0, stream>>>(qk, vA, 512);
  // scores
  gemm_nt<256><<<512, 256, 0, stream>>>(sc, sc, 512);
  softmax_kernel<<<16384, 256, 0, stream>>>(S);
  // PV: attnT[m][c] = sum_j P[m][j] vB[b][c][j]
  gemm_nt<128><<<512, 256, 0, stream>>>(pv, pv, 512);
  // proj + resid
  gemm_nt<128><<<512, 256, 0, stream>>>(pj, pj, 512);
}